// Round 6
// baseline (1222.054 us; speedup 1.0000x reference)
//
#include <hip/hip_runtime.h>
#include <hip/hip_bf16.h>

// Problem: N=2048, F_IN=128, F_OUT=64
// out[j,f] = sum_{i,k} A[j,i] H[i,f] mh[i,k] H[k,f] mf[j,k],  H = X@W + b
// R7 (resubmit; previous round died on container infra, no kernel verdict).
// Barrier-free per-wave pipeline: R6 showed occupancy is register-capped at
// 2 blocks/CU (240 regs) and acc-shrink is LDS-read-bound -- so attack
// OVERLAP at fixed occupancy: each wave stages a PRIVATE copy of exactly the
// A/B tile halves it reads (2x LDS write dup, L1-absorbed on fetch side), so
// the main loop needs NO __syncthreads. Per-wave double-buffer with counted
// vmcnt(8) on the wave's own global_load_lds; waves self-pace -> MFMA burst
// of one wave covers the other's ds_read/VALU prep on the same SIMD.
// All address/swizzle/epilogue patterns byte-identical to R6 (verified
// correct, 0 bank conflicts). Lessons kept: acc=128 regs max (R3), no
// per-instr sched pins (R4), 16x16x32 shape (R5), k-split x2 grid (R6).

typedef __attribute__((ext_vector_type(8))) _Float16 f16x8;
typedef __attribute__((ext_vector_type(4))) _Float16 f16x4;
typedef __attribute__((ext_vector_type(4))) float f32x4;

#define N 2048
#define FOUT 64
#define FIN 128
#define NIT 512        // 8 ktiles (per k-half) * 64 i-steps

#define MFMA16(A,B,C) __builtin_amdgcn_mfma_f32_16x16x32_f16((A),(B),(C),0,0,0)

__device__ __forceinline__ void gl_lds16(const _Float16* g, _Float16* l) {
    __builtin_amdgcn_global_load_lds(
        (const __attribute__((address_space(1))) void*)g,
        (__attribute__((address_space(3))) void*)l, 16, 0, 0);
}

// ---------------- prep kernels ----------------

__global__ __launch_bounds__(256) void k_zero(float* __restrict__ out) {
    ((float4*)out)[blockIdx.x * 256 + threadIdx.x] = make_float4(0.f, 0.f, 0.f, 0.f);
}

__global__ __launch_bounds__(256) void k_h(const float* __restrict__ X,
                                           const float* __restrict__ W,
                                           const float* __restrict__ bias,
                                           float* __restrict__ HT,
                                           _Float16* __restrict__ HTh) {
    __shared__ float Ws[FIN * FOUT];
    __shared__ float Xs[4 * FIN];
    int t = threadIdx.x;
#pragma unroll
    for (int s = 0; s < 32; ++s) Ws[t + 256 * s] = W[t + 256 * s];
    int i0 = blockIdx.x * 4;
#pragma unroll
    for (int s = 0; s < 2; ++s) { int idx = t + 256 * s; Xs[idx] = X[(size_t)i0 * FIN + idx]; }
    __syncthreads();
    int f = t & 63, il = t >> 6;
    float h = bias[f];
#pragma unroll
    for (int p = 0; p < FIN; ++p) h = fmaf(Xs[il * FIN + p], Ws[p * FOUT + f], h);
    int i = i0 + il;
    HT[f * N + i] = h;
    HTh[f * N + i] = (_Float16)h;
}

__global__ __launch_bounds__(256) void k_a2h(const float* __restrict__ A,
                                             _Float16* __restrict__ Ah) {
    int g = blockIdx.x * 256 + threadIdx.x;
    float4 v = ((const float4*)A)[g];
    f16x4 o;
    o[0] = (_Float16)v.x; o[1] = (_Float16)v.y; o[2] = (_Float16)v.z; o[3] = (_Float16)v.w;
    ((f16x4*)Ah)[g] = o;
}

__global__ __launch_bounds__(256) void k_mht(const float* __restrict__ mh,
                                             _Float16* __restrict__ mhT) {
    __shared__ float tile[64][65];
    int t = threadIdx.x;
    int bx = blockIdx.x & 31;
    int by = blockIdx.x >> 5;
#pragma unroll
    for (int s = 0; s < 16; ++s) {
        int lin = t + 256 * s;
        int r = lin >> 6, c = lin & 63;
        tile[r][c] = mh[(size_t)(by * 64 + r) * N + bx * 64 + c];
    }
    __syncthreads();
#pragma unroll
    for (int s = 0; s < 16; ++s) {
        int lin = t + 256 * s;
        int kr = lin >> 6, ic = lin & 63;
        mhT[(size_t)(bx * 64 + kr) * N + by * 64 + ic] = (_Float16)tile[ic][kr];
    }
}

// ---------------- main kernel ----------------
// grid 1024 = 16 jtiles (bid>>6) * 32 fgroups ((bid>>1)&31) * 2 khalves (bid&1).
// Per k-half: 8 ktiles (128k) x 64 i-steps (BI=32). Wave w: wj=(w&1)*64,
// wk=(w>>1)*64; wave stages ITS OWN A rows [wj,wj+64) and B rows [wk,wk+64)
// into tiles[w] (private): no cross-wave LDS deps -> no main-loop barriers.
// Row = 32 halves = 4 chunks of 16B; phys_chunk = log ^ ((row>>1)&3)
// (R6-verified conflict-free for both staging writes and b128 frag reads).

#define WAITV8 { asm volatile("s_waitcnt vmcnt(8)" ::: "memory"); __builtin_amdgcn_sched_barrier(0); }
#define WAITV0 { asm volatile("s_waitcnt vmcnt(0)" ::: "memory"); __builtin_amdgcn_sched_barrier(0); }
#define SB0 __builtin_amdgcn_sched_barrier(0);

// stage iteration IT's private tile halves into tiles[w][DBUF] (8 gl_lds)
#define STAGE(DBUF, IT)                                                        \
  {                                                                            \
    int ib_ = ((IT) & 63) << 5;                                                \
    int kt_ = (IT) >> 6;                                                       \
    const _Float16* pa_ = Ah + a_base + ib_;                                   \
    const _Float16* pb_ = mhT + b_base + (size_t)kt_ * 128 * N + ib_;          \
    _Float16* la_ = &tiles[w][DBUF][0][0];                                     \
    _Float16* lb_ = &tiles[w][DBUF][1][0];                                     \
    _Pragma("unroll")                                                          \
    for (int c_ = 0; c_ < 4; ++c_) {                                           \
      gl_lds16(pa_ + c_ * 16 * N, la_ + c_ * 512);                             \
      gl_lds16(pb_ + c_ * 16 * N, lb_ + c_ * 512);                             \
    }                                                                          \
  }

#define COMPUTE_HALF(BUF, IT)                                                  \
  {                                                                            \
    const char* hb_ = (const char*)hbuf + (((IT) & 63) << 6);                  \
    f16x8 ar[4], br[4];                                                        \
    _Pragma("unroll")                                                          \
    for (int x_ = 0; x_ < 4; ++x_)                                             \
      ar[x_] = *(const f16x8*)(tbase + frbA + (BUF) * 8192 + x_ * 1024);       \
    _Pragma("unroll")                                                          \
    for (int x_ = 0; x_ < 4; ++x_)                                             \
      br[x_] = *(const f16x8*)(tbase + frbB + (BUF) * 8192 + x_ * 1024);       \
    f16x8 h0 = *(const f16x8*)(hb_ + hq);                                      \
    f16x8 h1 = *(const f16x8*)(hb_ + 4096 + hq);                               \
    __builtin_amdgcn_s_setprio(1);                                             \
    _Pragma("unroll")                                                          \
    for (int jj = 0; jj < 4; ++jj) {                                           \
      f16x8 a0 = ar[jj] * h0;                                                  \
      f16x8 a1 = ar[jj] * h1;                                                  \
      _Pragma("unroll")                                                        \
      for (int kk = 0; kk < 4; ++kk) {                                         \
        acc[0][jj][kk] = MFMA16(a0, br[kk], acc[0][jj][kk]);                   \
        acc[1][jj][kk] = MFMA16(a1, br[kk], acc[1][jj][kk]);                   \
      }                                                                        \
    }                                                                          \
    __builtin_amdgcn_s_setprio(0);                                             \
    if (((IT) & 63) == 63) EPILOGUE(IT)                                        \
  }

#define EPILOGUE(IT)                                                           \
  {                                                                            \
    int kb_ = khalf + (((IT) >> 6) << 7);                                      \
    _Pragma("unroll")                                                          \
    for (int jj = 0; jj < 4; ++jj) {                                           \
      float t0[4] = {0.f, 0.f, 0.f, 0.f};                                      \
      float t1[4] = {0.f, 0.f, 0.f, 0.f};                                      \
      int jrow = jbase + wj + jj * 16 + q * 4;                                 \
      _Pragma("unroll")                                                        \
      for (int kk = 0; kk < 4; ++kk) {                                         \
        int kg = kb_ + wk + kk * 16 + l16;                                     \
        float hk0 = HT[f0 * N + kg];                                           \
        float hk1 = HT[(f0 + 1) * N + kg];                                     \
        _Pragma("unroll")                                                      \
        for (int r = 0; r < 4; ++r) {                                          \
          float m = mf[(size_t)(jrow + r) * N + kg];                           \
          t0[r] = fmaf(acc[0][jj][kk][r], m * hk0, t0[r]);                     \
          t1[r] = fmaf(acc[1][jj][kk][r], m * hk1, t1[r]);                     \
        }                                                                      \
      }                                                                        \
      _Pragma("unroll")                                                        \
      for (int r = 0; r < 4; ++r) {                                            \
        float v0 = t0[r], v1 = t1[r];                                          \
        v0 += __shfl_xor(v0, 1); v1 += __shfl_xor(v1, 1);                      \
        v0 += __shfl_xor(v0, 2); v1 += __shfl_xor(v1, 2);                      \
        v0 += __shfl_xor(v0, 4); v1 += __shfl_xor(v1, 4);                      \
        v0 += __shfl_xor(v0, 8); v1 += __shfl_xor(v1, 8);                      \
        if (l16 == 0) {                                                        \
          red[0][w][jj * 16 + q * 4 + r] += v0;                                \
          red[1][w][jj * 16 + q * 4 + r] += v1;                                \
        }                                                                      \
      }                                                                        \
    }                                                                          \
    _Pragma("unroll")                                                          \
    for (int a_ = 0; a_ < 4; ++a_)                                             \
      _Pragma("unroll")                                                        \
      for (int b_ = 0; b_ < 4; ++b_) {                                         \
        acc[0][a_][b_] = (f32x4){0.f, 0.f, 0.f, 0.f};                          \
        acc[1][a_][b_] = (f32x4){0.f, 0.f, 0.f, 0.f};                          \
      }                                                                        \
  }

__global__ __launch_bounds__(256, 2) void k_main(const float* __restrict__ mf,
                                                 const float* __restrict__ HT,
                                                 const _Float16* __restrict__ HTh,
                                                 const _Float16* __restrict__ Ah,
                                                 const _Float16* __restrict__ mhT,
                                                 float* __restrict__ out) {
    __shared__ _Float16 tiles[4][2][2][2048];   // [wave][buf][A/B][64r*32h] 64KB
    __shared__ _Float16 hbuf[2][N];             // H fp16 rows for f0,f1: 8KB
    __shared__ float red[2][4][64];             // 2KB

    int t = threadIdx.x;
    int jbase = (blockIdx.x >> 6) << 7;
    int f0 = ((blockIdx.x >> 1) & 31) << 1;
    int khalf = (blockIdx.x & 1) << 10;         // 0 or 1024
    int w = t >> 6, lane = t & 63, q = lane >> 4, l16 = lane & 15;
    int wj = (w & 1) << 6, wk = (w >> 1) << 6;

    // --- stage H rows (once; cross-wave, covered by the single barrier) ---
#pragma unroll
    for (int s = 0; s < 2; ++s) {
        int idx = t + 256 * s;                // 0..511 ; fi=idx>>8, chunk=idx&255
        ((f16x8*)hbuf)[idx] = *(const f16x8*)&HTh[(size_t)(f0 + (idx >> 8)) * N + (idx & 255) * 8];
    }
    ((float*)red)[t] = 0.f;
    ((float*)red)[t + 256] = 0.f;

    // --- staging source offsets (per-wave private tiles; lane -> +lane*16B) ---
    // per call: 16 rows x 32 halves; lane -> (row_in = lane>>2, phys = lane&3);
    // source logical chunk = phys ^ ((row>>1)&3) = (lane&3) ^ ((lane>>3)&3)
    int chlog = (lane & 3) ^ ((lane >> 3) & 3);
    size_t a_base = (size_t)(jbase + wj + (lane >> 2)) * N + chlog * 8;
    size_t b_base = (size_t)(khalf + wk + (lane >> 2)) * N + chlog * 8;

    // --- hoisted fragment read addresses (bytes into private tile) ---
    const char* tbase = (const char*)&tiles[0][0][0][0];
    int chr = (q ^ ((l16 >> 1) & 3)) * 16;     // phys chunk byte offset
    int frbA = w * 16384 + l16 * 64 + chr;     // + x*1024 per 16-row group
    int frbB = frbA + 4096;
    int hq = q * 16;

    // --- prefetch iteration 0 (private; barrier below also drains it) ---
    STAGE(0, 0)
    __syncthreads();                           // hbuf/red visible to all waves

    f32x4 acc[2][4][4];
#pragma unroll
    for (int a = 0; a < 4; ++a)
#pragma unroll
        for (int b = 0; b < 4; ++b) {
            acc[0][a][b] = (f32x4){0.f, 0.f, 0.f, 0.f};
            acc[1][a][b] = (f32x4){0.f, 0.f, 0.f, 0.f};
        }

    // --- main loop: NO barriers; per-wave counted-vmcnt double buffer ---
    for (int tp = 0; tp < NIT / 2; ++tp) {
        int it0 = tp * 2;
        // ---- half A: prefetch(it0+1)->buf1, compute(it0) from buf0 ----
        SB0
        STAGE(1, it0 + 1)
        WAITV8                                 // own stage(it0) complete
        COMPUTE_HALF(0, it0)
        // ---- half B: prefetch(it0+2)->buf0, compute(it0+1) from buf1 ----
        SB0
        if (tp != NIT / 2 - 1) {
            STAGE(0, it0 + 2)
            WAITV8                             // own stage(it0+1) complete
        } else {
            WAITV0                             // drain last stage
        }
        COMPUTE_HALF(1, it0 + 1)
    }

    // --- cross-wave reduce + atomic add into out (2 k-halves sum here) ---
    __syncthreads();
    if (t < 128) {
        int j = t;
#pragma unroll
        for (int fi = 0; fi < 2; ++fi) {
            float v = (j < 64) ? (red[fi][0][j] + red[fi][2][j])
                               : (red[fi][1][j - 64] + red[fi][3][j - 64]);
            atomicAdd(&out[(size_t)(jbase + j) * FOUT + f0 + fi], v);
        }
    }
}

// ---------------- launch ----------------
extern "C" void kernel_launch(void* const* d_in, const int* in_sizes, int n_in,
                              void* d_out, int out_size, void* d_ws, size_t ws_size,
                              hipStream_t stream) {
    const float* X    = (const float*)d_in[0];
    const float* A    = (const float*)d_in[1];
    const float* mf   = (const float*)d_in[2];
    const float* mh   = (const float*)d_in[3];
    const float* W    = (const float*)d_in[4];
    const float* bias = (const float*)d_in[5];
    float* out = (float*)d_out;

    float*    HT  = (float*)d_ws;
    _Float16* HTh = (_Float16*)((char*)d_ws + 524288);
    _Float16* Ah  = (_Float16*)((char*)d_ws + 1048576);
    _Float16* mhT = (_Float16*)((char*)d_ws + 1048576 + 8388608);

    k_zero<<<(N * FOUT / 4) / 256, 256, 0, stream>>>(out);
    k_h<<<N / 4, 256, 0, stream>>>(X, W, bias, HT, HTh);
    k_a2h<<<(N * N / 4) / 256, 256, 0, stream>>>(A, Ah);
    k_mht<<<(N / 64) * (N / 64), 256, 0, stream>>>(mh, mhT);
    k_main<<<16 * 32 * 2, 256, 0, stream>>>(mf, HT, HTh, Ah, mhT, out);
}

// Round 7
// 1042.318 us; speedup vs baseline: 1.1724x; 1.1724x over previous
//
#include <hip/hip_runtime.h>
#include <hip/hip_bf16.h>

// Problem: N=2048, F_IN=128, F_OUT=64
// out[j,f] = sum_{i,k} A[j,i] H[i,f] mh[i,k] H[k,f] mf[j,k],  H = X@W + b
// R8 = R2 (best verified, 1015us) + ONE change: anti-phase stagger of the
// two co-resident blocks per CU. Corrected HW model: MFMA 16x16x32 costs
// ~19.4 SIMD-cyc (m06's 4.85 was per-CU); R2's period 4769 cyc/iter =
// 2484 (2 waves' MFMA) + 2x1150 (both preps) -> phases fully serialized,
// blocks dispatched in-phase and barrier-locked there. Delaying one block
// ~1200 cyc puts its MFMA window over the twin's prep (separate pipes).
// Stagger bit (bid ^ bid>>8)&1 covers both plausible same-CU pairings.

typedef __attribute__((ext_vector_type(8))) _Float16 f16x8;
typedef __attribute__((ext_vector_type(4))) _Float16 f16x4;
typedef __attribute__((ext_vector_type(4))) float f32x4;

#define N 2048
#define FOUT 64
#define FIN 128
#define BI 64          // i-tile per stage
#define NIT 512        // 16 ktiles * 32 i-steps

__device__ __forceinline__ void gl_lds16(const _Float16* g, _Float16* l) {
    __builtin_amdgcn_global_load_lds(
        (const __attribute__((address_space(1))) void*)g,
        (__attribute__((address_space(3))) void*)l, 16, 0, 0);
}

// ---------------- prep kernels ----------------

__global__ __launch_bounds__(256) void k_h(const float* __restrict__ X,
                                           const float* __restrict__ W,
                                           const float* __restrict__ bias,
                                           float* __restrict__ HT,
                                           _Float16* __restrict__ HTh) {
    __shared__ float Ws[FIN * FOUT];
    __shared__ float Xs[4 * FIN];
    int t = threadIdx.x;
#pragma unroll
    for (int s = 0; s < 32; ++s) Ws[t + 256 * s] = W[t + 256 * s];
    int i0 = blockIdx.x * 4;
#pragma unroll
    for (int s = 0; s < 2; ++s) { int idx = t + 256 * s; Xs[idx] = X[(size_t)i0 * FIN + idx]; }
    __syncthreads();
    int f = t & 63, il = t >> 6;
    float h = bias[f];
#pragma unroll
    for (int p = 0; p < FIN; ++p) h = fmaf(Xs[il * FIN + p], Ws[p * FOUT + f], h);
    int i = i0 + il;
    HT[f * N + i] = h;
    HTh[f * N + i] = (_Float16)h;
}

__global__ __launch_bounds__(256) void k_a2h(const float* __restrict__ A,
                                             _Float16* __restrict__ Ah) {
    int g = blockIdx.x * 256 + threadIdx.x;
    float4 v = ((const float4*)A)[g];
    f16x4 o;
    o[0] = (_Float16)v.x; o[1] = (_Float16)v.y; o[2] = (_Float16)v.z; o[3] = (_Float16)v.w;
    ((f16x4*)Ah)[g] = o;
}

__global__ __launch_bounds__(256) void k_mht(const float* __restrict__ mh,
                                             _Float16* __restrict__ mhT) {
    __shared__ float tile[64][65];
    int t = threadIdx.x;
    int bx = blockIdx.x & 31;
    int by = blockIdx.x >> 5;
#pragma unroll
    for (int s = 0; s < 16; ++s) {
        int lin = t + 256 * s;
        int r = lin >> 6, c = lin & 63;
        tile[r][c] = mh[(size_t)(by * 64 + r) * N + bx * 64 + c];
    }
    __syncthreads();
#pragma unroll
    for (int s = 0; s < 16; ++s) {
        int lin = t + 256 * s;
        int kr = lin >> 6, ic = lin & 63;
        mhT[(size_t)(bx * 64 + kr) * N + by * 64 + ic] = (_Float16)tile[ic][kr];
    }
}

// ---------------- main kernel ----------------
// grid 512 = 16 jtiles (bid>>5) * 32 fgroups (bid&31); block = 128j x 128k x 2f.
// Wave w: wj=(w&1)*64, wk=(w>>1)*64; per-wave 64x64 per f.
// LDS tile row = 64 halves = 8 chunks of 16B; phys_chunk = log_chunk ^ (row&7).
__global__ __launch_bounds__(256, 2) void k_main(const float* __restrict__ mf,
                                                 const float* __restrict__ HT,
                                                 const _Float16* __restrict__ HTh,
                                                 const _Float16* __restrict__ Ah,
                                                 const _Float16* __restrict__ mhT,
                                                 float* __restrict__ out) {
    __shared__ _Float16 tiles[2][2][128 * BI];  // [buf][a=0/b=1][row*64+..] 64KB
    __shared__ _Float16 hbuf[2][N];             // H fp16 rows for f0,f1: 8KB
    __shared__ float red[2][4][64];             // 2KB

    int t = threadIdx.x;
    int jbase = (blockIdx.x >> 5) << 7;
    int f0 = (blockIdx.x & 31) << 1;
    int w = t >> 6, lane = t & 63, q = lane >> 4, l16 = lane & 15;
    int wj = (w & 1) << 6, wk = (w >> 1) << 6;

    // --- stage H rows (once) ---
#pragma unroll
    for (int s = 0; s < 2; ++s) {
        int idx = t + 256 * s;                // 0..511 ; fi=idx>>8, chunk=idx&255
        ((f16x8*)hbuf)[idx] = *(const f16x8*)&HTh[(size_t)(f0 + (idx >> 8)) * N + (idx & 255) * 8];
    }

    // --- R8: anti-phase stagger (half-period ~1200 cyc) for one block of
    // each co-resident pair. Uniform branch; block-internal sync preserved.
    if (((blockIdx.x ^ (blockIdx.x >> 8)) & 1) != 0) {
        __builtin_amdgcn_s_sleep(15);          // ~960 cyc
        __builtin_amdgcn_s_sleep(4);           // ~256 cyc
    }

    // --- staging voffsets (global_load_lds: lane l -> ldsbase + l*16) ---
    int lrow = lane >> 3;                      // row within 8-row call
    int lchunk = (lane & 7) ^ lrow;            // logical chunk (XOR swizzle)
    // halves offsets, call c adds c*8*N, i-step adds ibase
    int a_base = (jbase + w * 32 + lrow) * N + lchunk * 8;
    int b_base = (w * 32 + lrow) * N + lchunk * 8;   // + kbase*N per ktile
    int lds_w = w * 2048;                      // (w*32 rows)*64 halves

    float outp[2][4][4];
#pragma unroll
    for (int fi = 0; fi < 2; ++fi)
#pragma unroll
        for (int a = 0; a < 4; ++a)
#pragma unroll
            for (int b = 0; b < 4; ++b) outp[fi][a][b] = 0.f;

    // --- prefetch iteration 0 ---
    {
        const _Float16* pa = Ah + a_base;
        const _Float16* pb = mhT + b_base;
        _Float16* la = &tiles[0][0][lds_w];
        _Float16* lb = &tiles[0][1][lds_w];
#pragma unroll
        for (int c = 0; c < 4; ++c) {
            gl_lds16(pa + c * 8 * N, la + c * 512);
            gl_lds16(pb + c * 8 * N, lb + c * 512);
        }
    }

    f32x4 acc[2][4][4];
#pragma unroll
    for (int fi = 0; fi < 2; ++fi)
#pragma unroll
        for (int a = 0; a < 4; ++a)
#pragma unroll
            for (int b = 0; b < 4; ++b) acc[fi][a][b] = (f32x4){0.f, 0.f, 0.f, 0.f};

    for (int it = 0; it < NIT; ++it) {
        int buf = it & 1;
        int ibase = (it & 31) << 6;
        int kbase = (it >> 5) << 7;

        __syncthreads();   // drains prefetch(it) [vmcnt0] + frees other buffer

        // --- prefetch it+1 into other buffer (overlaps compute below) ---
        if (it + 1 < NIT) {
            int ib2 = ((it + 1) & 31) << 6;
            int kt2 = (it + 1) >> 5;
            const _Float16* pa = Ah + a_base + ib2;
            const _Float16* pb = mhT + b_base + kt2 * 128 * N + ib2;
            _Float16* la = &tiles[buf ^ 1][0][lds_w];
            _Float16* lb = &tiles[buf ^ 1][1][lds_w];
#pragma unroll
            for (int c = 0; c < 4; ++c) {
                gl_lds16(pa + c * 8 * N, la + c * 512);
                gl_lds16(pb + c * 8 * N, lb + c * 512);
            }
        }

        // --- compute from tiles[buf] ---
        const _Float16* ta = tiles[buf][0];
        const _Float16* tb = tiles[buf][1];
#pragma unroll
        for (int s = 0; s < 2; ++s) {
            f16x8 ar[4], br[4];
#pragma unroll
            for (int x = 0; x < 4; ++x) {
                int row = wj + x * 16 + l16;
                ar[x] = *(const f16x8*)&ta[row * 64 + (((q + 4 * s) ^ (l16 & 7)) * 8)];
            }
#pragma unroll
            for (int x = 0; x < 4; ++x) {
                int row = wk + x * 16 + l16;
                br[x] = *(const f16x8*)&tb[row * 64 + (((q + 4 * s) ^ (l16 & 7)) * 8)];
            }
            f16x8 h0 = *(const f16x8*)&hbuf[0][ibase + s * 32 + q * 8];
            f16x8 h1 = *(const f16x8*)&hbuf[1][ibase + s * 32 + q * 8];
#pragma unroll
            for (int jj = 0; jj < 4; ++jj) {
                f16x8 a0 = ar[jj] * h0;
                f16x8 a1 = ar[jj] * h1;
#pragma unroll
                for (int kk = 0; kk < 4; ++kk) {
                    acc[0][jj][kk] = __builtin_amdgcn_mfma_f32_16x16x32_f16(a0, br[kk], acc[0][jj][kk], 0, 0, 0);
                    acc[1][jj][kk] = __builtin_amdgcn_mfma_f32_16x16x32_f16(a1, br[kk], acc[1][jj][kk], 0, 0, 0);
                }
            }
        }

        // --- per-ktile epilogue: fold k into out-partials ---
        if ((it & 31) == 31) {
#pragma unroll
            for (int jj = 0; jj < 4; ++jj) {
                float t0[4] = {0.f, 0.f, 0.f, 0.f};
                float t1[4] = {0.f, 0.f, 0.f, 0.f};
#pragma unroll
                for (int kk = 0; kk < 4; ++kk) {
                    int kg = kbase + wk + kk * 16 + l16;
                    float hk0 = HT[f0 * N + kg];
                    float hk1 = HT[(f0 + 1) * N + kg];
                    int jrow = jbase + wj + jj * 16 + q * 4;
#pragma unroll
                    for (int r = 0; r < 4; ++r) {
                        float m = mf[(size_t)(jrow + r) * N + kg];
                        t0[r] = fmaf(acc[0][jj][kk][r], m * hk0, t0[r]);
                        t1[r] = fmaf(acc[1][jj][kk][r], m * hk1, t1[r]);
                    }
                }
#pragma unroll
                for (int r = 0; r < 4; ++r) {
                    float v0 = t0[r], v1 = t1[r];
                    v0 += __shfl_xor(v0, 1); v1 += __shfl_xor(v1, 1);
                    v0 += __shfl_xor(v0, 2); v1 += __shfl_xor(v1, 2);
                    v0 += __shfl_xor(v0, 4); v1 += __shfl_xor(v1, 4);
                    v0 += __shfl_xor(v0, 8); v1 += __shfl_xor(v1, 8);
                    outp[0][jj][r] += v0;
                    outp[1][jj][r] += v1;
                }
            }
#pragma unroll
            for (int fi = 0; fi < 2; ++fi)
#pragma unroll
                for (int a = 0; a < 4; ++a)
#pragma unroll
                    for (int b = 0; b < 4; ++b) acc[fi][a][b] = (f32x4){0.f, 0.f, 0.f, 0.f};
        }
    }

    // --- cross-wave reduce + store ---
    if (l16 == 0) {
#pragma unroll
        for (int fi = 0; fi < 2; ++fi)
#pragma unroll
            for (int jj = 0; jj < 4; ++jj)
#pragma unroll
                for (int r = 0; r < 4; ++r)
                    red[fi][w][jj * 16 + q * 4 + r] = outp[fi][jj][r];
    }
    __syncthreads();
    if (t < 128) {
        int j = t;
#pragma unroll
        for (int fi = 0; fi < 2; ++fi) {
            float v = (j < 64) ? (red[fi][0][j] + red[fi][2][j])
                               : (red[fi][1][j - 64] + red[fi][3][j - 64]);
            out[(size_t)(jbase + j) * FOUT + f0 + fi] = v;
        }
    }
}

// ---------------- launch ----------------
extern "C" void kernel_launch(void* const* d_in, const int* in_sizes, int n_in,
                              void* d_out, int out_size, void* d_ws, size_t ws_size,
                              hipStream_t stream) {
    const float* X    = (const float*)d_in[0];
    const float* A    = (const float*)d_in[1];
    const float* mf   = (const float*)d_in[2];
    const float* mh   = (const float*)d_in[3];
    const float* W    = (const float*)d_in[4];
    const float* bias = (const float*)d_in[5];
    float* out = (float*)d_out;

    float*    HT  = (float*)d_ws;
    _Float16* HTh = (_Float16*)((char*)d_ws + 524288);
    _Float16* Ah  = (_Float16*)((char*)d_ws + 1048576);
    _Float16* mhT = (_Float16*)((char*)d_ws + 1048576 + 8388608);

    k_h<<<N / 4, 256, 0, stream>>>(X, W, bias, HT, HTh);
    k_a2h<<<(N * N / 4) / 256, 256, 0, stream>>>(A, Ah);
    k_mht<<<(N / 64) * (N / 64), 256, 0, stream>>>(mh, mhT);
    k_main<<<16 * 32, 256, 0, stream>>>(mf, HT, HTh, Ah, mhT, out);
}

// Round 8
// 1020.484 us; speedup vs baseline: 1.1975x; 1.0214x over previous
//
#include <hip/hip_runtime.h>
#include <hip/hip_bf16.h>

// Problem: N=2048, F_IN=128, F_OUT=64
// out[j,f] = sum_{i,k} A[j,i] H[i,f] mh[i,k] H[k,f] mf[j,k],  H = X@W + b
// R9 = R2 (best, 1015us) restructured into a 4-phase counted-vmcnt schedule
// (m201/T3+T4+T5 port). R8's stagger null + dynamics: in-phase lockstep is
// the ATTRACTOR under shared-LDS-port contention; one-shot delays decay. The
// proven fix is structural: small {read cluster | MFMA cluster} phases with
// raw s_barriers (no vmcnt drain) so wave slip interleaves reads under
// MFMAs. setprio now sits in its proven regime (phased schedule, m218b).
// Addresses/swizzle/epilogue byte-identical to R2 (verified, 0 conflicts).
// vmcnt(0) only at iter top (drained loads >= 3 phases old). s1 frag reads
// deferred to P2 to keep VGPR <= 128 (2 waves/SIMD hard requirement).

typedef __attribute__((ext_vector_type(8))) _Float16 f16x8;
typedef __attribute__((ext_vector_type(4))) _Float16 f16x4;
typedef __attribute__((ext_vector_type(4))) float f32x4;

#define N 2048
#define FOUT 64
#define FIN 128
#define BI 64          // i-tile per stage
#define NIT 512        // 16 ktiles * 32 i-steps

#define MFMA16(A,B,C) __builtin_amdgcn_mfma_f32_16x16x32_f16((A),(B),(C),0,0,0)
#define BARS  { __builtin_amdgcn_s_barrier(); __builtin_amdgcn_sched_barrier(0); }
#define LGKM0 { asm volatile("s_waitcnt lgkmcnt(0)" ::: "memory"); __builtin_amdgcn_sched_barrier(0); }
#define VM0   { asm volatile("s_waitcnt vmcnt(0)" ::: "memory"); __builtin_amdgcn_sched_barrier(0); }

__device__ __forceinline__ void gl_lds16(const _Float16* g, _Float16* l) {
    __builtin_amdgcn_global_load_lds(
        (const __attribute__((address_space(1))) void*)g,
        (__attribute__((address_space(3))) void*)l, 16, 0, 0);
}

// ---------------- prep kernels ----------------

__global__ __launch_bounds__(256) void k_h(const float* __restrict__ X,
                                           const float* __restrict__ W,
                                           const float* __restrict__ bias,
                                           float* __restrict__ HT,
                                           _Float16* __restrict__ HTh) {
    __shared__ float Ws[FIN * FOUT];
    __shared__ float Xs[4 * FIN];
    int t = threadIdx.x;
#pragma unroll
    for (int s = 0; s < 32; ++s) Ws[t + 256 * s] = W[t + 256 * s];
    int i0 = blockIdx.x * 4;
#pragma unroll
    for (int s = 0; s < 2; ++s) { int idx = t + 256 * s; Xs[idx] = X[(size_t)i0 * FIN + idx]; }
    __syncthreads();
    int f = t & 63, il = t >> 6;
    float h = bias[f];
#pragma unroll
    for (int p = 0; p < FIN; ++p) h = fmaf(Xs[il * FIN + p], Ws[p * FOUT + f], h);
    int i = i0 + il;
    HT[f * N + i] = h;
    HTh[f * N + i] = (_Float16)h;
}

__global__ __launch_bounds__(256) void k_a2h(const float* __restrict__ A,
                                             _Float16* __restrict__ Ah) {
    int g = blockIdx.x * 256 + threadIdx.x;
    float4 v = ((const float4*)A)[g];
    f16x4 o;
    o[0] = (_Float16)v.x; o[1] = (_Float16)v.y; o[2] = (_Float16)v.z; o[3] = (_Float16)v.w;
    ((f16x4*)Ah)[g] = o;
}

__global__ __launch_bounds__(256) void k_mht(const float* __restrict__ mh,
                                             _Float16* __restrict__ mhT) {
    __shared__ float tile[64][65];
    int t = threadIdx.x;
    int bx = blockIdx.x & 31;
    int by = blockIdx.x >> 5;
#pragma unroll
    for (int s = 0; s < 16; ++s) {
        int lin = t + 256 * s;
        int r = lin >> 6, c = lin & 63;
        tile[r][c] = mh[(size_t)(by * 64 + r) * N + bx * 64 + c];
    }
    __syncthreads();
#pragma unroll
    for (int s = 0; s < 16; ++s) {
        int lin = t + 256 * s;
        int kr = lin >> 6, ic = lin & 63;
        mhT[(size_t)(bx * 64 + kr) * N + by * 64 + ic] = (_Float16)tile[ic][kr];
    }
}

// ---------------- main kernel ----------------
// grid 512 = 16 jtiles (bid>>5) * 32 fgroups (bid&31); block = 128j x 128k x 2f.
// Wave w: wj=(w&1)*64, wk=(w>>1)*64; per-wave 64x64 per f.
// LDS tile row = 64 halves = 8 chunks of 16B; phys_chunk = log_chunk ^ (row&7).
__global__ __launch_bounds__(256, 2) void k_main(const float* __restrict__ mf,
                                                 const float* __restrict__ HT,
                                                 const _Float16* __restrict__ HTh,
                                                 const _Float16* __restrict__ Ah,
                                                 const _Float16* __restrict__ mhT,
                                                 float* __restrict__ out) {
    __shared__ _Float16 tiles[2][2][128 * BI];  // [buf][a=0/b=1][row*64+..] 64KB
    __shared__ _Float16 hbuf[2][N];             // H fp16 rows for f0,f1: 8KB
    __shared__ float red[2][4][64];             // 2KB

    int t = threadIdx.x;
    int jbase = (blockIdx.x >> 5) << 7;
    int f0 = (blockIdx.x & 31) << 1;
    int w = t >> 6, lane = t & 63, q = lane >> 4, l16 = lane & 15;
    int wj = (w & 1) << 6, wk = (w >> 1) << 6;

    // --- stage H rows (once) ---
#pragma unroll
    for (int s = 0; s < 2; ++s) {
        int idx = t + 256 * s;                // 0..511 ; fi=idx>>8, chunk=idx&255
        ((f16x8*)hbuf)[idx] = *(const f16x8*)&HTh[(size_t)(f0 + (idx >> 8)) * N + (idx & 255) * 8];
    }

    // --- staging voffsets (global_load_lds: lane l -> ldsbase + l*16) ---
    int lrow = lane >> 3;                      // row within 8-row call
    int lchunk = (lane & 7) ^ lrow;            // logical chunk (XOR swizzle)
    int a_base = (jbase + w * 32 + lrow) * N + lchunk * 8;
    int b_base = (w * 32 + lrow) * N + lchunk * 8;   // + kbase*N per ktile
    int lds_w = w * 2048;                      // (w*32 rows)*64 halves

    float outp[2][4][4];
#pragma unroll
    for (int fi = 0; fi < 2; ++fi)
#pragma unroll
        for (int a = 0; a < 4; ++a)
#pragma unroll
            for (int b = 0; b < 4; ++b) outp[fi][a][b] = 0.f;

    // --- prefetch iteration 0 (all 8 calls) ---
    {
        const _Float16* pa = Ah + a_base;
        const _Float16* pb = mhT + b_base;
        _Float16* la = &tiles[0][0][lds_w];
        _Float16* lb = &tiles[0][1][lds_w];
#pragma unroll
        for (int c = 0; c < 4; ++c) {
            gl_lds16(pa + c * 8 * N, la + c * 512);
            gl_lds16(pb + c * 8 * N, lb + c * 512);
        }
    }

    f32x4 acc[2][4][4];
#pragma unroll
    for (int fi = 0; fi < 2; ++fi)
#pragma unroll
        for (int a = 0; a < 4; ++a)
#pragma unroll
            for (int b = 0; b < 4; ++b) acc[fi][a][b] = (f32x4){0.f, 0.f, 0.f, 0.f};

    __syncthreads();   // hbuf visible + stage(0) drained (full drain, prologue only)

    for (int it = 0; it < NIT; ++it) {
        int buf = it & 1;
        int ibase = (it & 31) << 6;
        int kbase = (it >> 5) << 7;
        const _Float16* ta = tiles[buf][0];
        const _Float16* tb = tiles[buf][1];
        bool more = (it + 1 < NIT);
        int ib2 = ((it + 1) & 31) << 6;
        int kt2 = (it + 1) >> 5;
        const _Float16* pa = Ah + a_base + ib2;
        const _Float16* pb = mhT + b_base + kt2 * 128 * N + ib2;
        _Float16* la = &tiles[buf ^ 1][0][lds_w];
        _Float16* lb = &tiles[buf ^ 1][1][lds_w];

        // ---- iter top: own stage(it) loads retired -> tile[buf] complete ----
        VM0
        BARS

        // ======== P0: read s0 frags + 4 stage calls | MFMA fi0*s0 ========
        f16x8 ar0[4], br0[4];
#pragma unroll
        for (int x = 0; x < 4; ++x)
            ar0[x] = *(const f16x8*)&ta[(wj + x * 16 + l16) * 64 + ((q ^ (l16 & 7)) * 8)];
#pragma unroll
        for (int x = 0; x < 4; ++x)
            br0[x] = *(const f16x8*)&tb[(wk + x * 16 + l16) * 64 + ((q ^ (l16 & 7)) * 8)];
        f16x8 h00 = *(const f16x8*)&hbuf[0][ibase + q * 8];
        f16x8 h10 = *(const f16x8*)&hbuf[1][ibase + q * 8];
        if (more) {
            gl_lds16(pa + 0 * 8 * N, la + 0 * 512);
            gl_lds16(pb + 0 * 8 * N, lb + 0 * 512);
            gl_lds16(pa + 1 * 8 * N, la + 1 * 512);
            gl_lds16(pb + 1 * 8 * N, lb + 1 * 512);
        }
        BARS
        LGKM0
        __builtin_amdgcn_s_setprio(1);
#pragma unroll
        for (int jj = 0; jj < 4; ++jj) {
            f16x8 a0 = ar0[jj] * h00;
#pragma unroll
            for (int kk = 0; kk < 4; ++kk)
                acc[0][jj][kk] = MFMA16(a0, br0[kk], acc[0][jj][kk]);
        }
        __builtin_amdgcn_s_setprio(0);

        // ======== P1: 4 stage calls | MFMA fi1*s0 (register-only) ========
        if (more) {
            gl_lds16(pa + 2 * 8 * N, la + 2 * 512);
            gl_lds16(pb + 2 * 8 * N, lb + 2 * 512);
            gl_lds16(pa + 3 * 8 * N, la + 3 * 512);
            gl_lds16(pb + 3 * 8 * N, lb + 3 * 512);
        }
        BARS
        __builtin_amdgcn_s_setprio(1);
#pragma unroll
        for (int jj = 0; jj < 4; ++jj) {
            f16x8 a1 = ar0[jj] * h10;
#pragma unroll
            for (int kk = 0; kk < 4; ++kk)
                acc[1][jj][kk] = MFMA16(a1, br0[kk], acc[1][jj][kk]);
        }
        __builtin_amdgcn_s_setprio(0);

        // ======== P2: read s1 frags | MFMA fi0*s1 ========
        f16x8 ar1[4], br1[4];
#pragma unroll
        for (int x = 0; x < 4; ++x)
            ar1[x] = *(const f16x8*)&ta[(wj + x * 16 + l16) * 64 + (((q + 4) ^ (l16 & 7)) * 8)];
#pragma unroll
        for (int x = 0; x < 4; ++x)
            br1[x] = *(const f16x8*)&tb[(wk + x * 16 + l16) * 64 + (((q + 4) ^ (l16 & 7)) * 8)];
        f16x8 h01 = *(const f16x8*)&hbuf[0][ibase + 32 + q * 8];
        f16x8 h11 = *(const f16x8*)&hbuf[1][ibase + 32 + q * 8];
        BARS
        LGKM0
        __builtin_amdgcn_s_setprio(1);
#pragma unroll
        for (int jj = 0; jj < 4; ++jj) {
            f16x8 a0 = ar1[jj] * h01;
#pragma unroll
            for (int kk = 0; kk < 4; ++kk)
                acc[0][jj][kk] = MFMA16(a0, br1[kk], acc[0][jj][kk]);
        }
        __builtin_amdgcn_s_setprio(0);

        // ======== P3: MFMA fi1*s1 (register-only) + ktile epilogue ========
        BARS
        __builtin_amdgcn_s_setprio(1);
#pragma unroll
        for (int jj = 0; jj < 4; ++jj) {
            f16x8 a1 = ar1[jj] * h11;
#pragma unroll
            for (int kk = 0; kk < 4; ++kk)
                acc[1][jj][kk] = MFMA16(a1, br1[kk], acc[1][jj][kk]);
        }
        __builtin_amdgcn_s_setprio(0);

        if ((it & 31) == 31) {
#pragma unroll
            for (int jj = 0; jj < 4; ++jj) {
                float t0[4] = {0.f, 0.f, 0.f, 0.f};
                float t1[4] = {0.f, 0.f, 0.f, 0.f};
#pragma unroll
                for (int kk = 0; kk < 4; ++kk) {
                    int kg = kbase + wk + kk * 16 + l16;
                    float hk0 = HT[f0 * N + kg];
                    float hk1 = HT[(f0 + 1) * N + kg];
                    int jrow = jbase + wj + jj * 16 + q * 4;
#pragma unroll
                    for (int r = 0; r < 4; ++r) {
                        float m = mf[(size_t)(jrow + r) * N + kg];
                        t0[r] = fmaf(acc[0][jj][kk][r], m * hk0, t0[r]);
                        t1[r] = fmaf(acc[1][jj][kk][r], m * hk1, t1[r]);
                    }
                }
#pragma unroll
                for (int r = 0; r < 4; ++r) {
                    float v0 = t0[r], v1 = t1[r];
                    v0 += __shfl_xor(v0, 1); v1 += __shfl_xor(v1, 1);
                    v0 += __shfl_xor(v0, 2); v1 += __shfl_xor(v1, 2);
                    v0 += __shfl_xor(v0, 4); v1 += __shfl_xor(v1, 4);
                    v0 += __shfl_xor(v0, 8); v1 += __shfl_xor(v1, 8);
                    outp[0][jj][r] += v0;
                    outp[1][jj][r] += v1;
                }
            }
#pragma unroll
            for (int fi = 0; fi < 2; ++fi)
#pragma unroll
                for (int a = 0; a < 4; ++a)
#pragma unroll
                    for (int b = 0; b < 4; ++b) acc[fi][a][b] = (f32x4){0.f, 0.f, 0.f, 0.f};
        }
    }

    // --- cross-wave reduce + store ---
    if (l16 == 0) {
#pragma unroll
        for (int fi = 0; fi < 2; ++fi)
#pragma unroll
            for (int jj = 0; jj < 4; ++jj)
#pragma unroll
                for (int r = 0; r < 4; ++r)
                    red[fi][w][jj * 16 + q * 4 + r] = outp[fi][jj][r];
    }
    __syncthreads();
    if (t < 128) {
        int j = t;
#pragma unroll
        for (int fi = 0; fi < 2; ++fi) {
            float v = (j < 64) ? (red[fi][0][j] + red[fi][2][j])
                               : (red[fi][1][j - 64] + red[fi][3][j - 64]);
            out[(size_t)(jbase + j) * FOUT + f0 + fi] = v;
        }
    }
}

// ---------------- launch ----------------
extern "C" void kernel_launch(void* const* d_in, const int* in_sizes, int n_in,
                              void* d_out, int out_size, void* d_ws, size_t ws_size,
                              hipStream_t stream) {
    const float* X    = (const float*)d_in[0];
    const float* A    = (const float*)d_in[1];
    const float* mf   = (const float*)d_in[2];
    const float* mh   = (const float*)d_in[3];
    const float* W    = (const float*)d_in[4];
    const float* bias = (const float*)d_in[5];
    float* out = (float*)d_out;

    float*    HT  = (float*)d_ws;
    _Float16* HTh = (_Float16*)((char*)d_ws + 524288);
    _Float16* Ah  = (_Float16*)((char*)d_ws + 1048576);
    _Float16* mhT = (_Float16*)((char*)d_ws + 1048576 + 8388608);

    k_h<<<N / 4, 256, 0, stream>>>(X, W, bias, HT, HTh);
    k_a2h<<<(N * N / 4) / 256, 256, 0, stream>>>(A, Ah);
    k_mht<<<(N / 64) * (N / 64), 256, 0, stream>>>(mh, mhT);
    k_main<<<16 * 32, 256, 0, stream>>>(mf, HT, HTh, Ah, mhT, out);
}